// Round 12
// baseline (156.911 us; speedup 1.0000x reference)
//
#include <hip/hip_runtime.h>

// Kalman filter, reformulated:  out[b][p] = alpha_p + sum_t Z[p][t] x[b][t]
// 21 blocks x 256, __launch_bounds__(256,1):
//   block 0    : ALL serial recursions, zero cross-block traffic in-loop.
//                wave 0: register Riccati (PF resident; U via LDS; k->kL ring)
//                wave 1 : V columns 0-15  (r4's D==B MFMA propagation, split-f16)
//                wave 2 : V columns 16-31
//                wave 3 : F_t stager (hi+lo f16 into FHI/FLO dbuf)
//                1 lds_barrier/step; W published once at end.
//   blocks 1-4 : prediction chains u_p, e_p (1 chain per wave)
//   blocks 5-20: output GEMM (256 batches each); gated by done-counter (=5)
// LDS (block0): QL[16][64][4]f32 @0 | FHI[2][16][64][4]f16 @16384
//               FLO[2][16][64][4]f16 @32768 | UL[16][64][4]f16 @49152
//               kL[4][64]f32 @57344   (total 58368)
// ws (u64): (unused 0..2047) | WP[33*64] | UP[16*64] | EP[16] | CNT

constexpr int WP_OFF = 2048;
constexpr int UP_OFF = 4160;
constexpr int EP_OFF = 5184;
constexpr int CNT_OFF = 5200;
constexpr int WS_U64 = 5201;

typedef float    f32x4 __attribute__((ext_vector_type(4)));
typedef _Float16 f16x4 __attribute__((ext_vector_type(4)));

#define MFMA16(a, b, c) __builtin_amdgcn_mfma_f32_16x16x16f16((a), (b), (c), 0, 0, 0)

template <int CTRL>
__device__ __forceinline__ float dpp_add(float x) {
  int v = __builtin_amdgcn_update_dpp(0, __builtin_bit_cast(int, x), CTRL, 0xf, 0xf, true);
  return x + __builtin_bit_cast(float, v);
}
__device__ __forceinline__ float sum16(float x) {  // full sum within 16-lane rows
  x = dpp_add<0xB1>(x);   // quad_perm xor1
  x = dpp_add<0x4E>(x);   // quad_perm xor2
  x = dpp_add<0x141>(x);  // row_half_mirror (xor4)
  x = dpp_add<0x140>(x);  // row_mirror (xor8)
  return x;
}
__device__ __forceinline__ float xrow_sum(float x) {  // sum across the 4 row-groups
  const float a = __shfl_xor(x, 16, 64);
  const float b = __shfl_xor(x, 32, 64);
  const float c = __shfl_xor(x, 48, 64);
  return (x + a) + (b + c);
}

__device__ __forceinline__ float spin_read(const unsigned long long* p, unsigned tag) {
  unsigned long long v = 0;
  for (int it = 0; it < (1 << 22); ++it) {
    v = __hip_atomic_load(p, __ATOMIC_RELAXED, __HIP_MEMORY_SCOPE_AGENT);
    if ((unsigned)(v >> 32) == tag) break;
  }
  union { unsigned u; float f; } cv; cv.u = (unsigned)v;
  return cv.f;
}
__device__ __forceinline__ void pub_write(unsigned long long* p, unsigned tag, float x) {
  union { float f; unsigned u; } cv; cv.f = x;
  __hip_atomic_store(p, ((unsigned long long)tag << 32) | cv.u,
                     __ATOMIC_RELAXED, __HIP_MEMORY_SCOPE_AGENT);
}
__device__ __forceinline__ void lds_barrier() {
  asm volatile("s_waitcnt lgkmcnt(0)" ::: "memory");
  __builtin_amdgcn_sched_barrier(0);
  __builtin_amdgcn_s_barrier();
  __builtin_amdgcn_sched_barrier(0);
}

__global__ __launch_bounds__(256, 1) void kalman_fused(
    const float* __restrict__ Fw, const float* __restrict__ Fb,
    const float* __restrict__ Hw, const float* __restrict__ Hb,
    const float* __restrict__ s0, const float* __restrict__ P0,
    const float* __restrict__ Qg, const float* __restrict__ Rg,
    const float* __restrict__ x, float* __restrict__ out,
    unsigned long long* __restrict__ ws) {
  __shared__ __align__(16) char smem[58368];
  const int tid  = threadIdx.x;
  const int lane = tid & 63;
  const int w    = tid >> 6;
  const int blk  = blockIdx.x;
  unsigned long long* wp = ws + WP_OFF;
  unsigned long long* up = ws + UP_OFF;
  unsigned long long* ep = ws + EP_OFF;

  if (blk == 0) {
    float*    QL  = (float*)smem;               // [16][64][4]
    _Float16* FHI = (_Float16*)(smem + 16384);  // [2][16][64][4]
    _Float16* FLO = (_Float16*)(smem + 32768);  // [2][16][64][4]
    _Float16* UL  = (_Float16*)(smem + 49152);  // [16][64][4]
    float*    kL  = (float*)(smem + 57344);     // [4][64]
    const int l15 = lane & 15, g = lane >> 4;

    // ---- prologue (all 4 waves): QL, F_0 -> FHI/FLO buf0 ----
    for (int slot = tid; slot < 1024; slot += 256) {
      const int f = slot >> 6, ln = slot & 63;
      const int a = f >> 2, b = f & 3, g2 = ln >> 4, l2 = ln & 15;
      f32x4 v;
      #pragma unroll
      for (int r = 0; r < 4; ++r)
        v[r] = Qg[(16 * a + 4 * g2 + r) * 64 + 16 * b + l2];
      *(f32x4*)&QL[slot * 4] = v;
    }
    for (int s = tid; s < 1024; s += 256) {
      const int r = s >> 4, c4 = (s & 15) * 4;
      const f32x4 v = *(const f32x4*)(Fw + r * 64 + c4);
      f16x4 hi, lo;
      #pragma unroll
      for (int j = 0; j < 4; ++j) {
        const _Float16 h_ = (_Float16)v[j];
        hi[j] = h_;
        lo[j] = (_Float16)((v[j] - (float)h_) * 2048.0f);
      }
      const int tile = (r >> 4) * 4 + (c4 >> 4);
      const int ln = (r & 15) + 16 * ((c4 & 15) >> 2);
      *(f16x4*)&FHI[(tile * 64 + ln) * 4] = hi;
      *(f16x4*)&FLO[(tile * 64 + ln) * 4] = lo;
    }
    __syncthreads();

    if (w == 3) {
      // ---- stager wave: F_{t+1} -> buf (t+1)&1 ----
      for (int t = 0; t < 32; ++t) {
        if (t + 1 < 32) {
          const float* Fbase = Fw + (size_t)(t + 1) * 4096;
          _Float16* dh = FHI + ((t + 1) & 1) * 4096;
          _Float16* dl = FLO + ((t + 1) & 1) * 4096;
          #pragma unroll
          for (int it = 0; it < 16; ++it) {
            const int s = lane + it * 64;
            const int r = s >> 4, c4 = (s & 15) * 4;
            const f32x4 v = *(const f32x4*)(Fbase + r * 64 + c4);
            f16x4 hi, lo;
            #pragma unroll
            for (int j = 0; j < 4; ++j) {
              const _Float16 h_ = (_Float16)v[j];
              hi[j] = h_;
              lo[j] = (_Float16)((v[j] - (float)h_) * 2048.0f);
            }
            const int tile = (r >> 4) * 4 + (c4 >> 4);
            const int ln = (r & 15) + 16 * ((c4 & 15) >> 2);
            *(f16x4*)&dh[(tile * 64 + ln) * 4] = hi;
            *(f16x4*)&dl[(tile * 64 + ln) * 4] = lo;
          }
        }
        lds_barrier();
      }
      pub_write(&wp[32 * 64 + lane], 1u, kL[3 * 64 + lane]);  // col32 = k_31
    } else if (w == 0) {
      // ---- wave 0: register Riccati ----
      const float R0 = Rg[0];
      f32x4 PF[4][4];  // D-frag: PF[a][b][r] = P[16a+4g+r][16b+l15]
      #pragma unroll
      for (int a = 0; a < 4; ++a)
        #pragma unroll
        for (int b = 0; b < 4; ++b)
          #pragma unroll
          for (int r = 0; r < 4; ++r)
            PF[a][b][r] = P0[(16 * a + 4 * g + r) * 64 + 16 * b + l15];
      f32x4 krow[4];
      float hpc[4] = {0.f, 0.f, 0.f, 0.f};
      #pragma unroll
      for (int a = 0; a < 4; ++a) krow[a] = (f32x4){0.f, 0.f, 0.f, 0.f};

      for (int t = 0; t < 32; ++t) {
        const _Float16* fh = FHI + (t & 1) * 4096;
        f16x4 Fh0[4];  // resident tj=0 B tiles
        #pragma unroll
        for (int kc = 0; kc < 4; ++kc)
          Fh0[kc] = *(const f16x4*)&fh[(kc * 64 + lane) * 4];
        // mm1: U tiles -> UL (split-f16 A)
        #pragma unroll
        for (int ti = 0; ti < 4; ++ti) {
          f16x4 Ah[4], Al[4];
          #pragma unroll
          for (int kc = 0; kc < 4; ++kc) {
            const f32x4 p4 = PF[kc][ti] - krow[kc] * hpc[ti];
            #pragma unroll
            for (int j = 0; j < 4; ++j) {
              const _Float16 h_ = (_Float16)p4[j];
              Ah[kc][j] = h_;
              Al[kc][j] = (_Float16)((p4[j] - (float)h_) * 2048.0f);
            }
          }
          #pragma unroll
          for (int tj = 0; tj < 4; ++tj) {
            f32x4 am = {0.f, 0.f, 0.f, 0.f}, a2 = {0.f, 0.f, 0.f, 0.f};
            #pragma unroll
            for (int kc = 0; kc < 4; ++kc) {
              const f16x4 bh = (tj == 0) ? Fh0[kc]
                  : *(const f16x4*)&fh[((tj * 4 + kc) * 64 + lane) * 4];
              am = MFMA16(Ah[kc], bh, am);
              a2 = MFMA16(Al[kc], bh, a2);
            }
            const f32x4 u = am + a2 * (1.0f / 2048.0f);
            f16x4 uh;
            #pragma unroll
            for (int j = 0; j < 4; ++j) uh[j] = (_Float16)u[j];
            *(f16x4*)&UL[((ti * 4 + tj) * 64 + lane) * 4] = uh;
          }
        }
        asm volatile("s_waitcnt lgkmcnt(0)" ::: "memory");
        __builtin_amdgcn_sched_barrier(0);
        // h for reductions (global, issued before mm2)
        f32x4 hrow[4];
        float hcol[4];
        #pragma unroll
        for (int a = 0; a < 4; ++a)
          hrow[a] = *(const f32x4*)(Hw + t * 64 + 16 * a + 4 * g);
        #pragma unroll
        for (int b = 0; b < 4; ++b) hcol[b] = Hw[t * 64 + 16 * b + l15];
        // mm2: Ppred = U^T F^T + Q
        #pragma unroll
        for (int ti = 0; ti < 4; ++ti) {
          f16x4 Ua[4];
          #pragma unroll
          for (int kc = 0; kc < 4; ++kc)
            Ua[kc] = *(const f16x4*)&UL[((kc * 4 + ti) * 64 + lane) * 4];
          #pragma unroll
          for (int tj = 0; tj < 4; ++tj) {
            f32x4 acc = *(const f32x4*)&QL[((ti * 4 + tj) * 64 + lane) * 4];
            #pragma unroll
            for (int kc = 0; kc < 4; ++kc) {
              const f16x4 bh = (tj == 0) ? Fh0[kc]
                  : *(const f16x4*)&fh[((tj * 4 + kc) * 64 + lane) * 4];
              acc = MFMA16(Ua[kc], bh, acc);
            }
            PF[ti][tj] = acc;
          }
        }
        // reductions -> num, hP, S; finalize k_t
        f32x4 numf[4];
        #pragma unroll
        for (int a = 0; a < 4; ++a) {
          f32x4 np = PF[a][0] * hcol[0] + PF[a][1] * hcol[1] +
                     PF[a][2] * hcol[2] + PF[a][3] * hcol[3];
          #pragma unroll
          for (int r = 0; r < 4; ++r) np[r] = sum16(np[r]);
          numf[a] = np;
        }
        #pragma unroll
        for (int b = 0; b < 4; ++b) {
          float hp = 0.f;
          #pragma unroll
          for (int a = 0; a < 4; ++a) {
            const f32x4 tv = hrow[a] * PF[a][b];
            hp += (tv.x + tv.y) + (tv.z + tv.w);
          }
          hpc[b] = xrow_sum(hp);
        }
        float sp = 0.f;
        #pragma unroll
        for (int a = 0; a < 4; ++a) {
          const f32x4 tv = hrow[a] * numf[a];
          sp += (tv.x + tv.y) + (tv.z + tv.w);
        }
        const float Sv = xrow_sum(sp);
        const float rcpS = 1.0f / (Sv + R0);
        #pragma unroll
        for (int a = 0; a < 4; ++a) krow[a] = numf[a] * rcpS;
        if (l15 == 0) {
          #pragma unroll
          for (int a = 0; a < 4; ++a)
            *(f32x4*)&kL[(t & 3) * 64 + 16 * a + 4 * g] = krow[a];
        }
        lds_barrier();
      }
    } else {
      // ---- waves 1,2: V-column propagation (r4 structure, k from kL ring) ----
      const int ct = w - 1;  // cols 16ct .. 16ct+15
      f16x4 VbH[4], VbL[4];
      #pragma unroll
      for (int kc = 0; kc < 4; ++kc) {
        const f32x4 s4 = *(const f32x4*)(s0 + 16 * kc + 4 * g);
        #pragma unroll
        for (int j = 0; j < 4; ++j) {
          const float v = (ct == 0 && l15 == 0) ? s4[j] : 0.f;
          const _Float16 h_ = (_Float16)v;
          VbH[kc][j] = h_;
          VbL[kc][j] = (_Float16)((v - (float)h_) * 2048.0f);
        }
      }
      f32x4 vpv[4];
      float qreg = 0.f;
      for (int t = 0; t < 32; ++t) {
        if (t > 0) {  // apply k_{t-1}; col t := k
          #pragma unroll
          for (int rt = 0; rt < 4; ++rt) {
            const f32x4 k4 = *(const f32x4*)&kL[((t - 1) & 3) * 64 + 16 * rt + 4 * g];
            #pragma unroll
            for (int j = 0; j < 4; ++j) {
              float val = vpv[rt][j] - k4[j] * qreg;
              if (l15 == t - 16 * ct) val = k4[j];
              const _Float16 h_ = (_Float16)val;
              VbH[rt][j] = h_;
              VbL[rt][j] = (_Float16)((val - (float)h_) * 2048.0f);
            }
          }
        }
        const _Float16* fh = FHI + (t & 1) * 4096;
        const _Float16* fl = FLO + (t & 1) * 4096;
        #pragma unroll
        for (int rt = 0; rt < 4; ++rt) {
          f32x4 am, a1;
          if (ct == 0 && l15 == 0) {
            const f32x4 fb4 = *(const f32x4*)(Fb + t * 64 + 16 * rt + 4 * g);
            am = fb4;
          } else {
            am = (f32x4){0.f, 0.f, 0.f, 0.f};
          }
          a1 = (f32x4){0.f, 0.f, 0.f, 0.f};
          #pragma unroll
          for (int kc = 0; kc < 4; ++kc) {
            const f16x4 ah = *(const f16x4*)&fh[((rt * 4 + kc) * 64 + lane) * 4];
            const f16x4 al = *(const f16x4*)&fl[((rt * 4 + kc) * 64 + lane) * 4];
            am = MFMA16(ah, VbH[kc], am);
            a1 = MFMA16(ah, VbL[kc], a1);
            a1 = MFMA16(al, VbH[kc], a1);
          }
          vpv[rt] = am + a1 * (1.0f / 2048.0f);
        }
        float qp = 0.f;
        #pragma unroll
        for (int rt = 0; rt < 4; ++rt) {
          const f32x4 h4 = *(const f32x4*)(Hw + t * 64 + 16 * rt + 4 * g);
          qp += h4.x * vpv[rt].x + h4.y * vpv[rt].y +
                h4.z * vpv[rt].z + h4.w * vpv[rt].w;
        }
        qp += __shfl_xor(qp, 16, 64);
        qp += __shfl_xor(qp, 32, 64);
        if (ct == 0 && l15 == 0) qp += Hb[t];
        qreg = qp;
        lds_barrier();
      }
      // final: apply k_31, publish W cols
      #pragma unroll
      for (int rt = 0; rt < 4; ++rt) {
        const f32x4 k4 = *(const f32x4*)&kL[3 * 64 + 16 * rt + 4 * g];
        #pragma unroll
        for (int j = 0; j < 4; ++j) {
          const float val = vpv[rt][j] - k4[j] * qreg;
          pub_write(&wp[(16 * ct + l15) * 64 + 16 * rt + 4 * g + j], 1u, val);
        }
      }
    }
    __syncthreads();
    if (tid == 0)
      __hip_atomic_fetch_add(&ws[CNT_OFF], 1ull, __ATOMIC_RELAXED, __HIP_MEMORY_SCOPE_AGENT);
    return;
  }

  if (blk <= 4) {
    // ============ prediction chains u_p, e_p (1 chain per wave) ============
    const int p = (blk - 1) * 4 + w;
    const int q = 32 + p;
    float r = Hw[q * 64 + lane];
    float eacc = 0.f;
    for (int s = 0; s <= p; ++s) {
      const int m = q - s;
      eacc += r * Fb[m * 64 + lane];
      const float* Fm = Fw + (size_t)m * 4096;
      float r0 = 0.f, r1 = 0.f, r2 = 0.f, r3 = 0.f;
      for (int j = 0; j < 64; j += 4) {
        r0 += __shfl(r, j,     64) * Fm[j * 64 + lane];
        r1 += __shfl(r, j + 1, 64) * Fm[(j + 1) * 64 + lane];
        r2 += __shfl(r, j + 2, 64) * Fm[(j + 2) * 64 + lane];
        r3 += __shfl(r, j + 3, 64) * Fm[(j + 3) * 64 + lane];
      }
      r = (r0 + r1) + (r2 + r3);
    }
    eacc = xrow_sum(sum16(eacc));
    pub_write(&up[p * 64 + lane], 1u, r);
    if (lane == 0) pub_write(&ep[p], 1u, eacc + Hb[q]);
    __syncthreads();
    if (tid == 0)
      __hip_atomic_fetch_add(&ws[CNT_OFF], 1ull, __ATOMIC_RELAXED, __HIP_MEMORY_SCOPE_AGENT);
    return;
  }

  // ================= output GEMM blocks (blk 5..20) =================
  {
    float* Ul = (float*)smem;             // [16][68]
    float* Wl = (float*)(smem + 4352);    // [33][68]
    float* Zl = (float*)(smem + 13328);   // [16][34]
    float* El = (float*)(smem + 15504);   // [16]
    const int b = (blk - 5) * 256 + tid;
    f32x4 xr[8];
    const f32x4* xp = (const f32x4*)(x + (size_t)b * 32);
    #pragma unroll
    for (int u = 0; u < 8; ++u) xr[u] = xp[u];

    if (tid == 0) {
      for (int it = 0; it < (1 << 22); ++it) {
        if (__hip_atomic_load(&ws[CNT_OFF], __ATOMIC_RELAXED, __HIP_MEMORY_SCOPE_AGENT) >= 5ull)
          break;
        __builtin_amdgcn_s_sleep(8);
      }
    }
    __syncthreads();
    for (int idx = tid; idx < 1024; idx += 256)
      Ul[(idx >> 6) * 68 + (idx & 63)] = spin_read(&up[idx], 1u);
    for (int idx = tid; idx < 2112; idx += 256)
      Wl[(idx >> 6) * 68 + (idx & 63)] = spin_read(&wp[idx], 1u);
    if (tid < 16) El[tid] = spin_read(&ep[tid], 1u);
    __syncthreads();
    for (int idx = tid; idx < 528; idx += 256) {
      const int p = idx / 33, cc = idx - p * 33;
      const float* Up = Ul + p * 68;
      const float* Wc = Wl + cc * 68;
      float a0 = 0.f, a1 = 0.f, a2 = 0.f, a3 = 0.f;
      #pragma unroll 4
      for (int i = 0; i < 64; i += 4) {
        a0 += Up[i] * Wc[i];         a1 += Up[i + 1] * Wc[i + 1];
        a2 += Up[i + 2] * Wc[i + 2]; a3 += Up[i + 3] * Wc[i + 3];
      }
      float z = (a0 + a1) + (a2 + a3);
      if (cc == 0) z += El[p];
      Zl[p * 34 + cc] = z;
    }
    __syncthreads();
    float acc[16];
    #pragma unroll
    for (int p = 0; p < 16; ++p) acc[p] = Zl[p * 34];
    #pragma unroll
    for (int u = 0; u < 8; ++u) {
      #pragma unroll
      for (int e = 0; e < 4; ++e) {
        const float xval = xr[u][e];
        const int t = u * 4 + e;
        #pragma unroll
        for (int p = 0; p < 16; ++p) acc[p] += Zl[p * 34 + 1 + t] * xval;
      }
    }
    float4* op = (float4*)(out + (size_t)b * 16);
    op[0] = make_float4(acc[0], acc[1], acc[2], acc[3]);
    op[1] = make_float4(acc[4], acc[5], acc[6], acc[7]);
    op[2] = make_float4(acc[8], acc[9], acc[10], acc[11]);
    op[3] = make_float4(acc[12], acc[13], acc[14], acc[15]);
  }
}

extern "C" void kernel_launch(void* const* d_in, const int* in_sizes, int n_in,
                              void* d_out, int out_size, void* d_ws, size_t ws_size,
                              hipStream_t stream) {
  (void)in_sizes; (void)n_in; (void)out_size; (void)ws_size;
  const float* x  = (const float*)d_in[0];
  const float* Fw = (const float*)d_in[1];
  const float* Fb = (const float*)d_in[2];
  const float* Hw = (const float*)d_in[3];
  const float* Hb = (const float*)d_in[4];
  const float* s0 = (const float*)d_in[5];
  const float* P0 = (const float*)d_in[6];
  const float* Q  = (const float*)d_in[7];
  const float* R  = (const float*)d_in[8];
  float* out = (float*)d_out;
  unsigned long long* ws = (unsigned long long*)d_ws;

  hipMemsetAsync(d_ws, 0, WS_U64 * sizeof(unsigned long long), stream);
  kalman_fused<<<21, 256, 0, stream>>>(Fw, Fb, Hw, Hb, s0, P0, Q, R, x, out, ws);
}

// Round 14
// 124.222 us; speedup vs baseline: 1.2631x; 1.2631x over previous
//
#include <hip/hip_runtime.h>

// Kalman filter, reformulated:  out[b][p] = alpha_p + sum_t Z[p][t] x[b][t]
// 27 blocks x 256, __launch_bounds__(256,1). r11 structure + packed-cvt wave0.
//   block 0    : 64x64 Riccati recursion -> gains k_t.
//                wave 0: all-register P recursion (PF/Uh/Fh resident), F/H/Q
//                  from LDS, barrier every 2 steps, packed f32->f16 cvts.
//                waves 1-3: stage 2 F matrices/period 1 period ahead (dbuf);
//                wave 1 publishes k ring after each barrier.
//   block 1    : prediction-phase row chains u_p, e_p (4 waves x 4 chains)
//   blocks 2-10: 33 V-column chains (1 wave each), consume tagged k_t
//   blocks 11-26: output GEMM (256 batches each); gated by done-counter
// LDS map (block 0): QL 0..16384 | HL 16384..24576 | FF 24576..57344
//                    kL 57344..58368
// ws (u64): KP[32*64] (tag t+1) | WP[33*64] | UP[16*64] | EP[16] | CNT

constexpr int KP_OFF = 0;
constexpr int WP_OFF = 2048;
constexpr int UP_OFF = 4160;
constexpr int EP_OFF = 5184;
constexpr int CNT_OFF = 5200;
constexpr int WS_U64 = 5201;

typedef float    f32x4 __attribute__((ext_vector_type(4)));
typedef _Float16 f16x4 __attribute__((ext_vector_type(4)));
typedef _Float16 f16x2 __attribute__((ext_vector_type(2)));
typedef __fp16   fp16x2 __attribute__((ext_vector_type(2)));  // cvt_pkrtz return type

#define MFMA16(a, b, c) __builtin_amdgcn_mfma_f32_16x16x16f16((a), (b), (c), 0, 0, 0)

__device__ __forceinline__ f16x4 cvt4_rtz(f32x4 v) {
  const f16x2 a = __builtin_bit_cast(f16x2, __builtin_amdgcn_cvt_pkrtz(v.x, v.y));
  const f16x2 b = __builtin_bit_cast(f16x2, __builtin_amdgcn_cvt_pkrtz(v.z, v.w));
  f16x4 r;
  r[0] = a[0]; r[1] = a[1]; r[2] = b[0]; r[3] = b[1];
  return r;
}
// split p into hi + lo*2^-11 (lo scaled by 2048); packed cvts
__device__ __forceinline__ void split4(f32x4 p, f16x4& hi, f16x4& lo) {
  hi = cvt4_rtz(p);
  f32x4 d;
  #pragma unroll
  for (int j = 0; j < 4; ++j) d[j] = (p[j] - (float)hi[j]) * 2048.0f;
  lo = cvt4_rtz(d);
}

template <int CTRL>
__device__ __forceinline__ float dpp_add(float x) {
  int v = __builtin_amdgcn_update_dpp(0, __builtin_bit_cast(int, x), CTRL, 0xf, 0xf, true);
  return x + __builtin_bit_cast(float, v);
}
__device__ __forceinline__ float sum16(float x) {  // full sum within 16-lane rows
  x = dpp_add<0xB1>(x);   // quad_perm xor1
  x = dpp_add<0x4E>(x);   // quad_perm xor2
  x = dpp_add<0x141>(x);  // row_half_mirror (xor4)
  x = dpp_add<0x140>(x);  // row_mirror (xor8)
  return x;
}
__device__ __forceinline__ float xrow_sum(float x) {
  const float a = __shfl_xor(x, 16, 64);
  const float b = __shfl_xor(x, 32, 64);
  const float c = __shfl_xor(x, 48, 64);
  return (x + a) + (b + c);
}

__device__ __forceinline__ float spin_read(const unsigned long long* p, unsigned tag) {
  unsigned long long v = 0;
  for (int it = 0; it < (1 << 22); ++it) {
    v = __hip_atomic_load(p, __ATOMIC_RELAXED, __HIP_MEMORY_SCOPE_AGENT);
    if ((unsigned)(v >> 32) == tag) break;
  }
  union { unsigned u; float f; } cv; cv.u = (unsigned)v;
  return cv.f;
}
__device__ __forceinline__ float spin_read_sleep(const unsigned long long* p, unsigned tag) {
  unsigned long long v = 0;
  for (int it = 0; it < (1 << 20); ++it) {
    v = __hip_atomic_load(p, __ATOMIC_RELAXED, __HIP_MEMORY_SCOPE_AGENT);
    if ((unsigned)(v >> 32) == tag) break;
    __builtin_amdgcn_s_sleep(2);
  }
  union { unsigned u; float f; } cv; cv.u = (unsigned)v;
  return cv.f;
}
__device__ __forceinline__ void pub_write(unsigned long long* p, unsigned tag, float x) {
  union { float f; unsigned u; } cv; cv.f = x;
  __hip_atomic_store(p, ((unsigned long long)tag << 32) | cv.u,
                     __ATOMIC_RELAXED, __HIP_MEMORY_SCOPE_AGENT);
}
__device__ __forceinline__ void lds_barrier() {
  asm volatile("s_waitcnt lgkmcnt(0)" ::: "memory");
  __builtin_amdgcn_sched_barrier(0);
  __builtin_amdgcn_s_barrier();
  __builtin_amdgcn_sched_barrier(0);
}

__global__ __launch_bounds__(256, 1) void kalman_fused(
    const float* __restrict__ Fw, const float* __restrict__ Fb,
    const float* __restrict__ Hw, const float* __restrict__ Hb,
    const float* __restrict__ s0, const float* __restrict__ P0,
    const float* __restrict__ Qg, const float* __restrict__ Rg,
    const float* __restrict__ x, float* __restrict__ out,
    unsigned long long* __restrict__ ws) {
  __shared__ __align__(16) char smem[58368];
  const int tid  = threadIdx.x;
  const int lane = tid & 63;
  const int w    = tid >> 6;
  const int blk  = blockIdx.x;
  unsigned long long* kp = ws + KP_OFF;
  unsigned long long* wp = ws + WP_OFF;
  unsigned long long* up = ws + UP_OFF;
  unsigned long long* ep = ws + EP_OFF;

  if (blk == 0) {
    float*    QL = (float*)smem;               // [16][64][4] Q D-frags (16 KB)
    float*    HL = (float*)(smem + 16384);     // [32][64] all H rows (8 KB)
    _Float16* FF = (_Float16*)(smem + 24576);  // [2buf][2mat][16][64][4] (32 KB)
    float*    kL = (float*)(smem + 57344);     // [4][64] k ring (1 KB)
    const int l15 = lane & 15, g = lane >> 4;

    // ---- prologue staging (all 4 waves): QL, HL, FF buf0 = F_0,F_1 ----
    for (int slot = tid; slot < 1024; slot += 256) {
      const int f = slot >> 6, ln = slot & 63;
      const int a = f >> 2, b = f & 3, g2 = ln >> 4, l2 = ln & 15;
      f32x4 v;
      #pragma unroll
      for (int r = 0; r < 4; ++r)
        v[r] = Qg[(16 * a + 4 * g2 + r) * 64 + 16 * b + l2];
      *(f32x4*)&QL[slot * 4] = v;
    }
    for (int idx = tid; idx < 2048; idx += 256) HL[idx] = Hw[idx];
    for (int s = tid; s < 2048; s += 256) {
      const int mat = s >> 10, s2 = s & 1023;
      const int r = s2 >> 4, c4 = (s2 & 15) * 4;
      const f32x4 v = *(const f32x4*)(Fw + mat * 4096 + r * 64 + c4);
      const f16x4 hf = cvt4_rtz(v);
      const int tile = (r >> 4) * 4 + (c4 >> 4);
      const int ln = (r & 15) + 16 * ((c4 & 15) >> 2);
      *(f16x4*)&FF[((mat * 16 + tile) * 64 + ln) * 4] = hf;
    }
    __syncthreads();

    if (w != 0) {
      // ---- stager waves 1-3: fill buf (c+1)&1 with F_{2c+2}, F_{2c+3} ----
      for (int c = 0; c < 16; ++c) {
        if (c < 15) {
          const float* Fbase = Fw + (size_t)(2 * c + 2) * 4096;
          _Float16* dstbuf = FF + (((c + 1) & 1) * 2 * 16) * 64 * 4;
          for (int s = (w - 1) * 64 + lane; s < 2048; s += 192) {
            const int mat = s >> 10, s2 = s & 1023;
            const int r = s2 >> 4, c4 = (s2 & 15) * 4;
            const f32x4 v = *(const f32x4*)(Fbase + mat * 4096 + r * 64 + c4);
            const f16x4 hf = cvt4_rtz(v);
            const int tile = (r >> 4) * 4 + (c4 >> 4);
            const int ln = (r & 15) + 16 * ((c4 & 15) >> 2);
            *(f16x4*)&dstbuf[((mat * 16 + tile) * 64 + ln) * 4] = hf;
          }
        }
        lds_barrier();
        if (w == 1) {  // publish k_{2c-1}, k_{2c} from the ring
          #pragma unroll
          for (int mm = 0; mm < 2; ++mm) {
            const int t = 2 * c - 1 + mm;
            if (t >= 0 && t <= 30)
              pub_write(&kp[t * 64 + lane], (unsigned)(t + 1), kL[(t & 3) * 64 + lane]);
          }
        }
      }
      return;
    }

    // ---- wave 0: the recursion ----
    const float R0 = Rg[0];
    f32x4 PF[4][4];   // D-frag: PF[a][b][r] = P[16a+4g+r][16b+l15]
    #pragma unroll
    for (int a = 0; a < 4; ++a)
      #pragma unroll
      for (int b = 0; b < 4; ++b)
        #pragma unroll
        for (int r = 0; r < 4; ++r)
          PF[a][b][r] = P0[(16 * a + 4 * g + r) * 64 + 16 * b + l15];

    f32x4 numf[4];
    float hpc[4] = {0.f, 0.f, 0.f, 0.f};
    float Sv = 0.f;
    #pragma unroll
    for (int a = 0; a < 4; ++a) numf[a] = (f32x4){0.f, 0.f, 0.f, 0.f};

    for (int c = 0; c < 16; ++c) {
      #pragma unroll
      for (int m = 0; m < 2; ++m) {
        const int t = 2 * c + m;
        // all 16 F frags resident (lane-linear b64, conflict-free)
        const _Float16* fsrc = FF + (((c & 1) * 2 + m) * 16) * 64 * 4;
        f16x4 Fh[4][4];
        #pragma unroll
        for (int a = 0; a < 4; ++a)
          #pragma unroll
          for (int b = 0; b < 4; ++b)
            Fh[a][b] = *(const f16x4*)&fsrc[((a * 4 + b) * 64 + lane) * 4];
        // h_t row/col forms from LDS
        f32x4 hrow[4];
        float hcol[4];
        #pragma unroll
        for (int a = 0; a < 4; ++a)
          hrow[a] = *(const f32x4*)&HL[t * 64 + 16 * a + 4 * g];
        #pragma unroll
        for (int b = 0; b < 4; ++b) hcol[b] = HL[t * 64 + 16 * b + l15];

        // k_{t-1}
        const float rcpS = 1.0f / (Sv + R0);
        f32x4 krow[4];
        #pragma unroll
        for (int a = 0; a < 4; ++a) krow[a] = numf[a] * rcpS;
        if (t > 0 && l15 == 0) {
          #pragma unroll
          for (int a = 0; a < 4; ++a)
            *(f32x4*)&kL[((t - 1) & 3) * 64 + 16 * a + 4 * g] = krow[a];
        }
        // mm1: U{ti,tj} = sum_kc Pw(kc,ti)^T F(tj,kc)^T  (packed split-A)
        f16x4 Uh[4][4];
        #pragma unroll
        for (int ti = 0; ti < 4; ++ti) {
          f16x4 Ah[4], Al[4];
          #pragma unroll
          for (int kc = 0; kc < 4; ++kc)
            split4(PF[kc][ti] - krow[kc] * hpc[ti], Ah[kc], Al[kc]);
          #pragma unroll
          for (int tj = 0; tj < 4; ++tj) {
            f32x4 am = {0.f, 0.f, 0.f, 0.f}, a2 = {0.f, 0.f, 0.f, 0.f};
            #pragma unroll
            for (int kc = 0; kc < 4; ++kc) {
              am = MFMA16(Ah[kc], Fh[tj][kc], am);
              a2 = MFMA16(Al[kc], Fh[tj][kc], a2);
            }
            Uh[ti][tj] = cvt4_rtz(am + a2 * (1.0f / 2048.0f));
          }
        }
        // mm2: Ppred{ti,tj} = sum_kc U(kc,ti)^T F(tj,kc)^T + Q (C from LDS)
        #pragma unroll
        for (int ti = 0; ti < 4; ++ti)
          #pragma unroll
          for (int tj = 0; tj < 4; ++tj) {
            f32x4 acc = *(const f32x4*)&QL[((ti * 4 + tj) * 64 + lane) * 4];
            #pragma unroll
            for (int kc = 0; kc < 4; ++kc)
              acc = MFMA16(Uh[kc][ti], Fh[tj][kc], acc);
            PF[ti][tj] = acc;
          }
        // reductions
        #pragma unroll
        for (int a = 0; a < 4; ++a) {
          f32x4 np = PF[a][0] * hcol[0] + PF[a][1] * hcol[1] +
                     PF[a][2] * hcol[2] + PF[a][3] * hcol[3];
          #pragma unroll
          for (int r = 0; r < 4; ++r) np[r] = sum16(np[r]);
          numf[a] = np;
        }
        #pragma unroll
        for (int b = 0; b < 4; ++b) {
          float hp = 0.f;
          #pragma unroll
          for (int a = 0; a < 4; ++a) {
            const f32x4 tv = hrow[a] * PF[a][b];
            hp += (tv.x + tv.y) + (tv.z + tv.w);
          }
          hpc[b] = xrow_sum(hp);
        }
        {
          float sp = 0.f;
          #pragma unroll
          for (int a = 0; a < 4; ++a) {
            const f32x4 tv = hrow[a] * numf[a];
            sp += (tv.x + tv.y) + (tv.z + tv.w);
          }
          Sv = xrow_sum(sp);
        }
      }
      lds_barrier();
    }
    // finalize + publish k_31 (via kL bounce, wave-local)
    {
      const float rcpS = 1.0f / (Sv + R0);
      if (l15 == 0) {
        #pragma unroll
        for (int a = 0; a < 4; ++a)
          *(f32x4*)&kL[3 * 64 + 16 * a + 4 * g] = numf[a] * rcpS;
      }
      asm volatile("s_waitcnt lgkmcnt(0)" ::: "memory");
      pub_write(&kp[31 * 64 + lane], 32u, kL[3 * 64 + lane]);
    }
    return;
  }

  if (blk == 1) {
    // ====== prediction-phase chains u_p, e_p (4 waves x 4 balanced chains) =====
    const int plist[4] = {w, 7 - w, 8 + w, 15 - w};
    #pragma unroll
    for (int pi = 0; pi < 4; ++pi) {
      const int p = plist[pi];
      const int q = 32 + p;
      float r = Hw[q * 64 + lane];
      float eacc = 0.f;
      for (int s = 0; s <= p; ++s) {
        const int m = q - s;
        eacc += r * Fb[m * 64 + lane];
        const float* Fm = Fw + (size_t)m * 4096;
        float r0 = 0.f, r1 = 0.f, r2 = 0.f, r3 = 0.f;
        for (int j = 0; j < 64; j += 4) {
          r0 += __shfl(r, j,     64) * Fm[j * 64 + lane];
          r1 += __shfl(r, j + 1, 64) * Fm[(j + 1) * 64 + lane];
          r2 += __shfl(r, j + 2, 64) * Fm[(j + 2) * 64 + lane];
          r3 += __shfl(r, j + 3, 64) * Fm[(j + 3) * 64 + lane];
        }
        r = (r0 + r1) + (r2 + r3);
      }
      eacc = xrow_sum(sum16(eacc));
      pub_write(&up[p * 64 + lane], 1u, r);
      if (lane == 0) pub_write(&ep[p], 1u, eacc + Hb[q]);
    }
    __syncthreads();
    if (tid == 0)
      __hip_atomic_fetch_add(&ws[CNT_OFF], 1ull, __ATOMIC_RELAXED, __HIP_MEMORY_SCOPE_AGENT);
    return;
  }

  if (blk < 11) {
    // ================= V-column chains (1 wave per column) =================
    float* vb = (float*)smem + w * 64;
    const int c = (blk - 2) * 4 + w;
    if (c > 32) return;
    if (c == 32) {  // w_31 = k_31
      pub_write(&wp[32 * 64 + lane], 1u, spin_read_sleep(&kp[31 * 64 + lane], 32u));
      if (lane == 0)
        __hip_atomic_fetch_add(&ws[CNT_OFF], 1ull, __ATOMIC_RELAXED, __HIP_MEMORY_SCOPE_AGENT);
      return;
    }
    const int t0 = (c == 0) ? 0 : c;
    float v = (c == 0) ? s0[lane] : spin_read_sleep(&kp[(c - 1) * 64 + lane], (unsigned)c);
    f32x4 fn[16];
    {
      const float* Fr = Fw + (size_t)t0 * 4096 + lane * 64;
      #pragma unroll
      for (int jc = 0; jc < 16; ++jc) fn[jc] = *(const f32x4*)(Fr + jc * 4);
    }
    float hn  = Hw[t0 * 64 + lane];
    float fbn = (c == 0) ? Fb[t0 * 64 + lane] : 0.f;
    for (int t = t0; t < 32; ++t) {
      vb[lane] = v;
      f32x4 fc[16];
      #pragma unroll
      for (int jc = 0; jc < 16; ++jc) fc[jc] = fn[jc];
      const float ht = hn, fbt = fbn;
      if (t + 1 < 32) {
        const float* Fr = Fw + (size_t)(t + 1) * 4096 + lane * 64;
        #pragma unroll
        for (int jc = 0; jc < 16; ++jc) fn[jc] = *(const f32x4*)(Fr + jc * 4);
        hn = Hw[(t + 1) * 64 + lane];
        if (c == 0) fbn = Fb[(t + 1) * 64 + lane];
      }
      float a0 = fbt, a1 = 0.f, a2 = 0.f, a3 = 0.f;
      #pragma unroll
      for (int jc = 0; jc < 16; ++jc) {
        const f32x4 vv = *(const f32x4*)(vb + jc * 4);
        a0 += fc[jc].x * vv.x; a1 += fc[jc].y * vv.y;
        a2 += fc[jc].z * vv.z; a3 += fc[jc].w * vv.w;
      }
      const float vp = (a0 + a1) + (a2 + a3);
      float hv = xrow_sum(sum16(ht * vp));
      if (c == 0) hv += Hb[t];
      const float kt = spin_read_sleep(&kp[t * 64 + lane], (unsigned)(t + 1));
      v = vp - kt * hv;
    }
    pub_write(&wp[c * 64 + lane], 1u, v);
    if (lane == 0)
      __hip_atomic_fetch_add(&ws[CNT_OFF], 1ull, __ATOMIC_RELAXED, __HIP_MEMORY_SCOPE_AGENT);
    return;
  }

  // ================= output GEMM blocks (blk 11..26) =================
  {
    float* Ul = (float*)smem;             // [16][68]
    float* Wl = (float*)(smem + 4352);    // [33][68]
    float* Zl = (float*)(smem + 13328);   // [16][34]
    float* El = (float*)(smem + 15504);   // [16]
    const int b = (blk - 11) * 256 + tid;
    f32x4 xr[8];
    const f32x4* xp = (const f32x4*)(x + (size_t)b * 32);
    #pragma unroll
    for (int u = 0; u < 8; ++u) xr[u] = xp[u];

    if (tid == 0) {
      for (int it = 0; it < (1 << 22); ++it) {
        if (__hip_atomic_load(&ws[CNT_OFF], __ATOMIC_RELAXED, __HIP_MEMORY_SCOPE_AGENT) >= 34ull)
          break;
        __builtin_amdgcn_s_sleep(8);
      }
    }
    __syncthreads();
    for (int idx = tid; idx < 1024; idx += 256)
      Ul[(idx >> 6) * 68 + (idx & 63)] = spin_read(&up[idx], 1u);
    for (int idx = tid; idx < 2112; idx += 256)
      Wl[(idx >> 6) * 68 + (idx & 63)] = spin_read(&wp[idx], 1u);
    if (tid < 16) El[tid] = spin_read(&ep[tid], 1u);
    __syncthreads();
    for (int idx = tid; idx < 528; idx += 256) {
      const int p = idx / 33, cc = idx - p * 33;
      const float* Up = Ul + p * 68;
      const float* Wc = Wl + cc * 68;
      float a0 = 0.f, a1 = 0.f, a2 = 0.f, a3 = 0.f;
      #pragma unroll 4
      for (int i = 0; i < 64; i += 4) {
        a0 += Up[i] * Wc[i];         a1 += Up[i + 1] * Wc[i + 1];
        a2 += Up[i + 2] * Wc[i + 2]; a3 += Up[i + 3] * Wc[i + 3];
      }
      float z = (a0 + a1) + (a2 + a3);
      if (cc == 0) z += El[p];
      Zl[p * 34 + cc] = z;
    }
    __syncthreads();
    float acc[16];
    #pragma unroll
    for (int p = 0; p < 16; ++p) acc[p] = Zl[p * 34];
    #pragma unroll
    for (int u = 0; u < 8; ++u) {
      #pragma unroll
      for (int e = 0; e < 4; ++e) {
        const float xval = xr[u][e];
        const int t = u * 4 + e;
        #pragma unroll
        for (int p = 0; p < 16; ++p) acc[p] += Zl[p * 34 + 1 + t] * xval;
      }
    }
    float4* op = (float4*)(out + (size_t)b * 16);
    op[0] = make_float4(acc[0], acc[1], acc[2], acc[3]);
    op[1] = make_float4(acc[4], acc[5], acc[6], acc[7]);
    op[2] = make_float4(acc[8], acc[9], acc[10], acc[11]);
    op[3] = make_float4(acc[12], acc[13], acc[14], acc[15]);
  }
}

extern "C" void kernel_launch(void* const* d_in, const int* in_sizes, int n_in,
                              void* d_out, int out_size, void* d_ws, size_t ws_size,
                              hipStream_t stream) {
  (void)in_sizes; (void)n_in; (void)out_size; (void)ws_size;
  const float* x  = (const float*)d_in[0];
  const float* Fw = (const float*)d_in[1];
  const float* Fb = (const float*)d_in[2];
  const float* Hw = (const float*)d_in[3];
  const float* Hb = (const float*)d_in[4];
  const float* s0 = (const float*)d_in[5];
  const float* P0 = (const float*)d_in[6];
  const float* Q  = (const float*)d_in[7];
  const float* R  = (const float*)d_in[8];
  float* out = (float*)d_out;
  unsigned long long* ws = (unsigned long long*)d_ws;

  (void)hipMemsetAsync(d_ws, 0, WS_U64 * sizeof(unsigned long long), stream);
  kalman_fused<<<27, 256, 0, stream>>>(Fw, Fb, Hw, Hb, s0, P0, Q, R, x, out, ws);
}